// Round 1
// baseline (179.868 us; speedup 1.0000x reference)
//
#include <hip/hip_runtime.h>

#define CFEAT 128
#define NODES 2048

__global__ __launch_bounds__(256) void symcon_kernel(
    const float* __restrict__ A,
    const float* __restrict__ Us1, const float* __restrict__ ws1,
    const float* __restrict__ Us2, const float* __restrict__ ws2,
    const float* __restrict__ Us3, const float* __restrict__ ws3,
    const float* __restrict__ Up1, const float* __restrict__ wp1,
    const float* __restrict__ Up2, const float* __restrict__ wp2,
    const float* __restrict__ Up3, const float* __restrict__ wp3,
    const float* __restrict__ Ud1, const float* __restrict__ wd1,
    const float* __restrict__ Ud2, const float* __restrict__ wd2,
    const float* __restrict__ Ud3, const float* __restrict__ wd3,
    float* __restrict__ out)
{
    const int c     = blockIdx.x;   // channel 0..127
    const int chunk = blockIdx.y;   // node chunk 0..3
    const int tid   = threadIdx.x;  // 0..255

    __shared__ float lW3[9 * 729];  // 26.2 KB
    __shared__ float lW2[9 * 81];   //  2.9 KB
    __shared__ float lW1[9 * 9];    //  0.3 KB

    // ---- per-channel effective weights: W = sum_k U[...,k] * w[k,c] ----
    // m_global ordering matches output concat: 0 = s, 1..3 = p, 4..8 = d
    for (int e = tid; e < 9 * 729; e += 256) {
        const int mg = e / 729, r = e - mg * 729;
        const float* U; const float* w; int k, ml;
        if (mg == 0)     { U = Us3; w = ws3; k = 5;  ml = 0; }
        else if (mg < 4) { U = Up3; w = wp3; k = 8;  ml = mg - 1; }
        else             { U = Ud3; w = wd3; k = 10; ml = mg - 4; }
        const float* u = U + (ml * 729 + r) * k;
        float s = 0.f;
        for (int kk = 0; kk < k; ++kk) s += u[kk] * w[kk * CFEAT + c];
        lW3[e] = s;
    }
    for (int e = tid; e < 9 * 81; e += 256) {
        const int mg = e / 81, r = e - mg * 81;
        const float* U; const float* w; int k, ml;
        if (mg == 0)     { U = Us2; w = ws2; k = 2; ml = 0; }
        else if (mg < 4) { U = Up2; w = wp2; k = 3; ml = mg - 1; }
        else             { U = Ud2; w = wd2; k = 4; ml = mg - 4; }
        const float* u = U + (ml * 81 + r) * k;
        float s = 0.f;
        for (int kk = 0; kk < k; ++kk) s += u[kk] * w[kk * CFEAT + c];
        lW2[e] = s;
    }
    if (tid < 81) {
        const int mg = tid / 9, r = tid - mg * 9;
        const float* U; const float* w; int ml;
        if (mg == 0)     { U = Us1; w = ws1; ml = 0; }
        else if (mg < 4) { U = Up1; w = wp1; ml = mg - 1; }
        else             { U = Ud1; w = wd1; ml = mg - 4; }
        lW1[tid] = U[ml * 9 + r] * w[c];   // k == 1 for all nu=1 paths
    }
    __syncthreads();

    // ---- hot loop: 2 nodes per thread, Horner-nested contraction ----
    const int b0 = chunk * 512 + tid;   // nodes b0 and b0+256 (2048 = 4*512 exact)
    const int b1 = b0 + 256;
    const float* A0 = A + (size_t)(b0 * CFEAT + c) * 9;
    const float* A1 = A + (size_t)(b1 * CFEAT + c) * 9;
    float a0[9], a1[9];
    #pragma unroll
    for (int i = 0; i < 9; ++i) { a0[i] = A0[i]; a1[i] = A1[i]; }

    float* O0 = out + (size_t)(b0 * CFEAT + c) * 9;
    float* O1 = out + (size_t)(b1 * CFEAT + c) * 9;

    #pragma unroll 1   // keep m rolled: bounds code size; i1/i2/i3 unrolled so a[] stays in VGPRs
    for (int m = 0; m < 9; ++m) {
        const float* w3m = &lW3[m * 729];
        const float* w2m = &lW2[m * 81];
        const float* w1m = &lW1[m * 9];
        float om0 = 0.f, om1 = 0.f;
        #pragma unroll
        for (int i1 = 0; i1 < 9; ++i1) {
            float s10 = w1m[i1], s11 = s10;
            #pragma unroll
            for (int i2 = 0; i2 < 9; ++i2) {
                float s20 = w2m[i1 * 9 + i2], s21 = s20;
                #pragma unroll
                for (int i3 = 0; i3 < 9; ++i3) {
                    const float w = w3m[(i1 * 9 + i2) * 9 + i3];
                    s20 = fmaf(w, a0[i3], s20);
                    s21 = fmaf(w, a1[i3], s21);
                }
                s10 = fmaf(s20, a0[i2], s10);
                s11 = fmaf(s21, a1[i2], s11);
            }
            om0 = fmaf(s10, a0[i1], om0);
            om1 = fmaf(s11, a1[i1], om1);
        }
        O0[m] = om0;
        O1[m] = om1;
    }
}

extern "C" void kernel_launch(void* const* d_in, const int* in_sizes, int n_in,
                              void* d_out, int out_size, void* d_ws, size_t ws_size,
                              hipStream_t stream)
{
    const float* A   = (const float*)d_in[0];
    const float* Us1 = (const float*)d_in[1];  const float* ws1 = (const float*)d_in[2];
    const float* Us2 = (const float*)d_in[3];  const float* ws2 = (const float*)d_in[4];
    const float* Us3 = (const float*)d_in[5];  const float* ws3 = (const float*)d_in[6];
    const float* Up1 = (const float*)d_in[7];  const float* wp1 = (const float*)d_in[8];
    const float* Up2 = (const float*)d_in[9];  const float* wp2 = (const float*)d_in[10];
    const float* Up3 = (const float*)d_in[11]; const float* wp3 = (const float*)d_in[12];
    const float* Ud1 = (const float*)d_in[13]; const float* wd1 = (const float*)d_in[14];
    const float* Ud2 = (const float*)d_in[15]; const float* wd2 = (const float*)d_in[16];
    const float* Ud3 = (const float*)d_in[17]; const float* wd3 = (const float*)d_in[18];
    float* out = (float*)d_out;

    dim3 grid(CFEAT, NODES / 512);
    symcon_kernel<<<grid, 256, 0, stream>>>(A, Us1, ws1, Us2, ws2, Us3, ws3,
                                            Up1, wp1, Up2, wp2, Up3, wp3,
                                            Ud1, wd1, Ud2, wd2, Ud3, wd3, out);
}

// Round 2
// 62.403 us; speedup vs baseline: 2.8823x; 2.8823x over previous
//
#include <hip/hip_runtime.h>

#define CFEAT 128
#define NODES 2048
#define NMONO 219            // 9 deg1 + 45 deg2 + 165 deg3
#define ROWF  12             // padded floats per monomial row (9 used)
#define WSZ   (NMONO * ROWF) // 2628 floats per channel

// ---- monomial index <-> (deg,i,j,l), i<=j<=l ------------------------------
// Order: idx 0..8 = deg1 (a_i); then for i<=j: one deg2 row (a_i a_j),
// followed by deg3 rows (a_i a_j a_l) for l=j..8. Must match hot loop order.
__device__ __forceinline__ void decode_idx(int idx, int& deg, int& i, int& j, int& l) {
    if (idx < 9) { deg = 1; i = idx; j = 0; l = 0; return; }
    int t = idx - 9;
    for (i = 0; i < 9; ++i) {
        for (j = i; j < 9; ++j) {
            int cnt = 10 - j;            // 1 deg2 + (9-j) deg3
            if (t < cnt) {
                if (t == 0) { deg = 2; l = 0; }
                else        { deg = 3; l = j + t - 1; }
                return;
            }
            t -= cnt;
        }
    }
    deg = 0;
}

template<int K>
__device__ __forceinline__ float dotk(const float* __restrict__ u,
                                      const float* __restrict__ w, int c) {
    float s = 0.f;
    #pragma unroll
    for (int kk = 0; kk < K; ++kk) s = fmaf(u[kk], w[kk * CFEAT + c], s);
    return s;
}

// Symmetrized coefficient of monomial (i<=j<=l) for channel c, local irrep ml.
template<int K2, int K3>
__device__ float mono_coeff(int deg, int i, int j, int l, int c, int ml,
    const float* __restrict__ U1, const float* __restrict__ w1,
    const float* __restrict__ U2, const float* __restrict__ w2,
    const float* __restrict__ U3, const float* __restrict__ w3)
{
    if (deg == 1) return U1[ml * 9 + i] * w1[c];              // k==1 for nu=1
    if (deg == 2) {
        float S = dotk<K2>(U2 + ((ml * 9 + i) * 9 + j) * K2, w2, c);
        if (i != j) S += dotk<K2>(U2 + ((ml * 9 + j) * 9 + i) * K2, w2, c);
        return S;
    }
    // deg 3: sum W3 over the distinct ordered permutations of (i,j,l)
    const int e0 = (i*9+j)*9+l, e1 = (i*9+l)*9+j, e2 = (j*9+i)*9+l,
              e3 = (j*9+l)*9+i, e4 = (l*9+i)*9+j, e5 = (l*9+j)*9+i;
    float S = dotk<K3>(U3 + (ml*729 + e0) * K3, w3, c);
    if (e1 != e0)                                           S += dotk<K3>(U3 + (ml*729+e1)*K3, w3, c);
    if (e2 != e0 && e2 != e1)                               S += dotk<K3>(U3 + (ml*729+e2)*K3, w3, c);
    if (e3 != e0 && e3 != e1 && e3 != e2)                   S += dotk<K3>(U3 + (ml*729+e3)*K3, w3, c);
    if (e4 != e0 && e4 != e1 && e4 != e2 && e4 != e3)       S += dotk<K3>(U3 + (ml*729+e4)*K3, w3, c);
    if (e5 != e0 && e5 != e1 && e5 != e2 && e5 != e3 && e5 != e4)
                                                            S += dotk<K3>(U3 + (ml*729+e5)*K3, w3, c);
    return S;
}

// ---- kernel 1: per-channel monomial coefficients into d_ws ----------------
__global__ __launch_bounds__(256) void symcon_prep(
    const float* __restrict__ Us1, const float* __restrict__ ws1,
    const float* __restrict__ Us2, const float* __restrict__ ws2,
    const float* __restrict__ Us3, const float* __restrict__ ws3,
    const float* __restrict__ Up1, const float* __restrict__ wp1,
    const float* __restrict__ Up2, const float* __restrict__ wp2,
    const float* __restrict__ Up3, const float* __restrict__ wp3,
    const float* __restrict__ Ud1, const float* __restrict__ wd1,
    const float* __restrict__ Ud2, const float* __restrict__ wd2,
    const float* __restrict__ Ud3, const float* __restrict__ wd3,
    float* __restrict__ Wm)
{
    const int c  = blockIdx.x;
    const int mg = blockIdx.y;   // global m: 0=s, 1..3=p, 4..8=d
    const int idx = threadIdx.x;
    if (idx >= NMONO) return;

    int deg, i, j, l;
    decode_idx(idx, deg, i, j, l);

    float v;
    if (mg == 0)
        v = mono_coeff<2,5>(deg, i, j, l, c, 0,      Us1, ws1, Us2, ws2, Us3, ws3);
    else if (mg < 4)
        v = mono_coeff<3,8>(deg, i, j, l, c, mg - 1, Up1, wp1, Up2, wp2, Up3, wp3);
    else
        v = mono_coeff<4,10>(deg, i, j, l, c, mg - 4, Ud1, wd1, Ud2, wd2, Ud3, wd3);

    float* row = Wm + (size_t)c * WSZ + idx * ROWF;
    row[mg] = v;
    if (mg == 0) { row[9] = 0.f; row[10] = 0.f; row[11] = 0.f; }
}

// ---- kernel 2: hot loop ----------------------------------------------------
template<bool FUSED>
__global__ __launch_bounds__(256, 2) void symcon_hot(
    const float* __restrict__ A, const float* __restrict__ Wmono,
    const float* __restrict__ Us1, const float* __restrict__ ws1,
    const float* __restrict__ Us2, const float* __restrict__ ws2,
    const float* __restrict__ Us3, const float* __restrict__ ws3,
    const float* __restrict__ Up1, const float* __restrict__ wp1,
    const float* __restrict__ Up2, const float* __restrict__ wp2,
    const float* __restrict__ Up3, const float* __restrict__ wp3,
    const float* __restrict__ Ud1, const float* __restrict__ wd1,
    const float* __restrict__ Ud2, const float* __restrict__ wd2,
    const float* __restrict__ Ud3, const float* __restrict__ wd3,
    float* __restrict__ out)
{
    const int c     = blockIdx.x;
    const int chunk = blockIdx.y;          // 8 chunks of 256 nodes
    const int tid   = threadIdx.x;

    __shared__ __align__(16) float lW[WSZ];   // 10512 B, broadcast-read
    __shared__ float sbuf[256 * 9];           // 9216 B, A in / out staging

    if (FUSED) {
        if (tid < NMONO) {
            int deg, i, j, l;
            decode_idx(tid, deg, i, j, l);
            float* row = lW + tid * ROWF;
            row[0] = mono_coeff<2,5>(deg, i, j, l, c, 0, Us1, ws1, Us2, ws2, Us3, ws3);
            #pragma unroll
            for (int ml = 0; ml < 3; ++ml)
                row[1 + ml] = mono_coeff<3,8>(deg, i, j, l, c, ml, Up1, wp1, Up2, wp2, Up3, wp3);
            #pragma unroll
            for (int ml = 0; ml < 5; ++ml)
                row[4 + ml] = mono_coeff<4,10>(deg, i, j, l, c, ml, Ud1, wd1, Ud2, wd2, Ud3, wd3);
            row[9] = row[10] = row[11] = 0.f;
        }
    } else {
        const float4* src = (const float4*)(Wmono + (size_t)c * WSZ);
        float4* dst = (float4*)lW;
        for (int e = tid; e < WSZ / 4; e += 256) dst[e] = src[e];
    }

    // stage A: nodes [b0, b0+256), fixed c — dense 36B chunks per node
    const int b0 = chunk * 256;
    const size_t gbase = ((size_t)b0 * CFEAT + c) * 9;
    for (int e = tid; e < 256 * 9; e += 256) {
        const int n = e / 9, q = e - n * 9;
        sbuf[e] = A[gbase + (size_t)n * (CFEAT * 9) + q];
    }
    __syncthreads();

    float a[9];
    #pragma unroll
    for (int q = 0; q < 9; ++q) a[q] = sbuf[tid * 9 + q];   // stride-9: 2-way only, free

    float acc[9] = {0.f,0.f,0.f,0.f,0.f,0.f,0.f,0.f,0.f};

    auto fma9 = [&](float x, int r) {
        #pragma unroll
        for (int m = 0; m < 9; ++m)
            acc[m] = fmaf(lW[r * ROWF + m], x, acc[m]);      // broadcast read
    };

    // deg1
    #pragma unroll
    for (int i = 0; i < 9; ++i) fma9(a[i], i);
    // deg2 + deg3, row order matches decode_idx
    int r = 9;
    #pragma unroll
    for (int i = 0; i < 9; ++i) {
        #pragma unroll
        for (int j = i; j < 9; ++j) {
            const float m2 = a[i] * a[j];
            fma9(m2, r); ++r;
            #pragma unroll
            for (int l = j; l < 9; ++l) { fma9(m2 * a[l], r); ++r; }
        }
    }

    // stage out through LDS (own region only -> no barrier needed before write)
    __syncthreads();   // make sure everyone is done reading lW/sbuf phase? (cheap, safe)
    #pragma unroll
    for (int m = 0; m < 9; ++m) sbuf[tid * 9 + m] = acc[m];
    __syncthreads();
    for (int e = tid; e < 256 * 9; e += 256) {
        const int n = e / 9, q = e - n * 9;
        out[gbase + (size_t)n * (CFEAT * 9) + q] = sbuf[e];
    }
}

extern "C" void kernel_launch(void* const* d_in, const int* in_sizes, int n_in,
                              void* d_out, int out_size, void* d_ws, size_t ws_size,
                              hipStream_t stream)
{
    const float* A   = (const float*)d_in[0];
    const float* Us1 = (const float*)d_in[1];  const float* ws1 = (const float*)d_in[2];
    const float* Us2 = (const float*)d_in[3];  const float* ws2 = (const float*)d_in[4];
    const float* Us3 = (const float*)d_in[5];  const float* ws3 = (const float*)d_in[6];
    const float* Up1 = (const float*)d_in[7];  const float* wp1 = (const float*)d_in[8];
    const float* Up2 = (const float*)d_in[9];  const float* wp2 = (const float*)d_in[10];
    const float* Up3 = (const float*)d_in[11]; const float* wp3 = (const float*)d_in[12];
    const float* Ud1 = (const float*)d_in[13]; const float* wd1 = (const float*)d_in[14];
    const float* Ud2 = (const float*)d_in[15]; const float* wd2 = (const float*)d_in[16];
    const float* Ud3 = (const float*)d_in[17]; const float* wd3 = (const float*)d_in[18];
    float* out = (float*)d_out;
    float* Wm  = (float*)d_ws;

    const bool use_ws = ws_size >= (size_t)CFEAT * WSZ * sizeof(float);
    if (use_ws) {
        symcon_prep<<<dim3(CFEAT, 9), 256, 0, stream>>>(
            Us1, ws1, Us2, ws2, Us3, ws3, Up1, wp1, Up2, wp2, Up3, wp3,
            Ud1, wd1, Ud2, wd2, Ud3, wd3, Wm);
        symcon_hot<false><<<dim3(CFEAT, NODES / 256), 256, 0, stream>>>(
            A, Wm, Us1, ws1, Us2, ws2, Us3, ws3, Up1, wp1, Up2, wp2, Up3, wp3,
            Ud1, wd1, Ud2, wd2, Ud3, wd3, out);
    } else {
        symcon_hot<true><<<dim3(CFEAT, NODES / 256), 256, 0, stream>>>(
            A, nullptr, Us1, ws1, Us2, ws2, Us3, ws3, Up1, wp1, Up2, wp2, Up3, wp3,
            Ud1, wd1, Ud2, wd2, Ud3, wd3, out);
    }
}

// Round 3
// 46.533 us; speedup vs baseline: 3.8654x; 1.3411x over previous
//
#include <hip/hip_runtime.h>

#define CFEAT 128
#define NODES 2048
#define NM    219            // 9 deg1 + 45 deg2 + 165 deg3
#define ROWF  16             // padded floats per monomial row (9 used; 64B rows)

// ---- monomial index <-> (deg,i,j,l), i<=j<=l ------------------------------
__device__ __forceinline__ void decode_idx(int idx, int& deg, int& i, int& j, int& l) {
    if (idx < 9) { deg = 1; i = idx; j = 0; l = 0; return; }
    int t = idx - 9;
    for (i = 0; i < 9; ++i) {
        for (j = i; j < 9; ++j) {
            int cnt = 10 - j;            // 1 deg2 + (9-j) deg3
            if (t < cnt) {
                if (t == 0) { deg = 2; l = 0; }
                else        { deg = 3; l = j + t - 1; }
                return;
            }
            t -= cnt;
        }
    }
    deg = 0;
}

template<int K>
__device__ __forceinline__ float dotk(const float* __restrict__ u,
                                      const float* __restrict__ w, int c) {
    float s = 0.f;
    #pragma unroll
    for (int kk = 0; kk < K; ++kk) s = fmaf(u[kk], w[kk * CFEAT + c], s);
    return s;
}

// Symmetrized coefficient of monomial (i<=j<=l) for channel c, local irrep ml.
template<int K2, int K3>
__device__ float mono_coeff(int deg, int i, int j, int l, int c, int ml,
    const float* __restrict__ U1, const float* __restrict__ w1,
    const float* __restrict__ U2, const float* __restrict__ w2,
    const float* __restrict__ U3, const float* __restrict__ w3)
{
    if (deg == 1) return U1[ml * 9 + i] * w1[c];              // k==1 for nu=1
    if (deg == 2) {
        float S = dotk<K2>(U2 + ((ml * 9 + i) * 9 + j) * K2, w2, c);
        if (i != j) S += dotk<K2>(U2 + ((ml * 9 + j) * 9 + i) * K2, w2, c);
        return S;
    }
    const int e0 = (i*9+j)*9+l, e1 = (i*9+l)*9+j, e2 = (j*9+i)*9+l,
              e3 = (j*9+l)*9+i, e4 = (l*9+i)*9+j, e5 = (l*9+j)*9+i;
    float S = dotk<K3>(U3 + (ml*729 + e0) * K3, w3, c);
    if (e1 != e0)                                           S += dotk<K3>(U3 + (ml*729+e1)*K3, w3, c);
    if (e2 != e0 && e2 != e1)                               S += dotk<K3>(U3 + (ml*729+e2)*K3, w3, c);
    if (e3 != e0 && e3 != e1 && e3 != e2)                   S += dotk<K3>(U3 + (ml*729+e3)*K3, w3, c);
    if (e4 != e0 && e4 != e1 && e4 != e2 && e4 != e3)       S += dotk<K3>(U3 + (ml*729+e4)*K3, w3, c);
    if (e5 != e0 && e5 != e1 && e5 != e2 && e5 != e3 && e5 != e4)
                                                            S += dotk<K3>(U3 + (ml*729+e5)*K3, w3, c);
    return S;
}

// ---- kernel 1: per-channel monomial coefficients into d_ws ----------------
__global__ __launch_bounds__(256) void symcon_prep(
    const float* __restrict__ Us1, const float* __restrict__ ws1,
    const float* __restrict__ Us2, const float* __restrict__ ws2,
    const float* __restrict__ Us3, const float* __restrict__ ws3,
    const float* __restrict__ Up1, const float* __restrict__ wp1,
    const float* __restrict__ Up2, const float* __restrict__ wp2,
    const float* __restrict__ Up3, const float* __restrict__ wp3,
    const float* __restrict__ Ud1, const float* __restrict__ wd1,
    const float* __restrict__ Ud2, const float* __restrict__ wd2,
    const float* __restrict__ Ud3, const float* __restrict__ wd3,
    float* __restrict__ Wm)
{
    const int c  = blockIdx.x;
    const int mg = blockIdx.y;   // global m: 0=s, 1..3=p, 4..8=d
    const int idx = threadIdx.x;
    if (idx >= NM) return;

    int deg, i, j, l;
    decode_idx(idx, deg, i, j, l);

    float v;
    if (mg == 0)
        v = mono_coeff<2,5>(deg, i, j, l, c, 0,      Us1, ws1, Us2, ws2, Us3, ws3);
    else if (mg < 4)
        v = mono_coeff<3,8>(deg, i, j, l, c, mg - 1, Up1, wp1, Up2, wp2, Up3, wp3);
    else
        v = mono_coeff<4,10>(deg, i, j, l, c, mg - 4, Ud1, wd1, Ud2, wd2, Ud3, wd3);

    Wm[(size_t)c * (NM * ROWF) + idx * ROWF + mg] = v;   // pads never read
}

// ---- kernel 2: hot loop ----------------------------------------------------
// FUSED=false: W read from global with wave-uniform addresses -> s_load (SMEM
// path, no LDS/VALU issue cost). FUSED=true: fallback, W built in LDS.
template<bool FUSED>
__global__ __launch_bounds__(256, 4) void symcon_hot(
    const float* __restrict__ A, const float* __restrict__ Wmono,
    const float* __restrict__ Us1, const float* __restrict__ ws1,
    const float* __restrict__ Us2, const float* __restrict__ ws2,
    const float* __restrict__ Us3, const float* __restrict__ ws3,
    const float* __restrict__ Up1, const float* __restrict__ wp1,
    const float* __restrict__ Up2, const float* __restrict__ wp2,
    const float* __restrict__ Up3, const float* __restrict__ wp3,
    const float* __restrict__ Ud1, const float* __restrict__ wd1,
    const float* __restrict__ Ud2, const float* __restrict__ wd2,
    const float* __restrict__ Ud3, const float* __restrict__ wd3,
    float* __restrict__ out)
{
    const int c     = blockIdx.x;
    const int chunk = blockIdx.y;          // 4 chunks of 512 nodes
    const int tid   = threadIdx.x;

    __shared__ float sbuf[512 * 9];                  // 18432 B: A in / out staging
    __shared__ float lW[FUSED ? NM * ROWF : 4];      // only used when FUSED

    if (FUSED) {
        if (tid < NM) {
            int deg, i, j, l;
            decode_idx(tid, deg, i, j, l);
            float* row = lW + tid * ROWF;
            row[0] = mono_coeff<2,5>(deg, i, j, l, c, 0, Us1, ws1, Us2, ws2, Us3, ws3);
            #pragma unroll
            for (int ml = 0; ml < 3; ++ml)
                row[1 + ml] = mono_coeff<3,8>(deg, i, j, l, c, ml, Up1, wp1, Up2, wp2, Up3, wp3);
            #pragma unroll
            for (int ml = 0; ml < 5; ++ml)
                row[4 + ml] = mono_coeff<4,10>(deg, i, j, l, c, ml, Ud1, wd1, Ud2, wd2, Ud3, wd3);
        }
    }

    // stage A: nodes [b0, b0+512), fixed c — dense 36B runs per node, coalesced e
    const int b0 = chunk * 512;
    const size_t gbase = ((size_t)b0 * CFEAT + c) * 9;
    for (int e = tid; e < 512 * 9; e += 256) {
        const int n = e / 9, q = e - n * 9;
        sbuf[e] = A[gbase + (size_t)n * (CFEAT * 9) + q];
    }
    __syncthreads();

    float a0[9], a1[9];
    #pragma unroll
    for (int q = 0; q < 9; ++q) {
        a0[q] = sbuf[tid * 9 + q];                   // stride-9: 2-way alias only (free)
        a1[q] = sbuf[(tid + 256) * 9 + q];
    }

    const float* __restrict__ Wc = Wmono + (size_t)c * (NM * ROWF);  // wave-uniform base

    float acc0[9] = {0,0,0,0,0,0,0,0,0};
    float acc1[9] = {0,0,0,0,0,0,0,0,0};

    auto fma2 = [&](float x0, float x1, int r) {
        #pragma unroll
        for (int m = 0; m < 9; ++m) {
            const float w = FUSED ? lW[r * ROWF + m] : Wc[r * ROWF + m];  // uniform -> s_load
            acc0[m] = fmaf(w, x0, acc0[m]);
            acc1[m] = fmaf(w, x1, acc1[m]);
        }
    };

    // deg1 rows 0..8
    #pragma unroll
    for (int i = 0; i < 9; ++i) fma2(a0[i], a1[i], i);
    // deg2 + deg3, row order matches decode_idx; full unroll keeps a[] in VGPRs
    int r = 9;
    #pragma unroll
    for (int i = 0; i < 9; ++i) {
        #pragma unroll
        for (int j = i; j < 9; ++j) {
            const float m20 = a0[i] * a0[j];
            const float m21 = a1[i] * a1[j];
            fma2(m20, m21, r); ++r;
            #pragma unroll
            for (int l = j; l < 9; ++l) {
                fma2(m20 * a0[l], m21 * a1[l], r); ++r;
            }
        }
    }

    // stage out through LDS -> coalesced global writes
    __syncthreads();
    #pragma unroll
    for (int m = 0; m < 9; ++m) {
        sbuf[tid * 9 + m]         = acc0[m];
        sbuf[(tid + 256) * 9 + m] = acc1[m];
    }
    __syncthreads();
    for (int e = tid; e < 512 * 9; e += 256) {
        const int n = e / 9, q = e - n * 9;
        out[gbase + (size_t)n * (CFEAT * 9) + q] = sbuf[e];
    }
}

extern "C" void kernel_launch(void* const* d_in, const int* in_sizes, int n_in,
                              void* d_out, int out_size, void* d_ws, size_t ws_size,
                              hipStream_t stream)
{
    const float* A   = (const float*)d_in[0];
    const float* Us1 = (const float*)d_in[1];  const float* ws1 = (const float*)d_in[2];
    const float* Us2 = (const float*)d_in[3];  const float* ws2 = (const float*)d_in[4];
    const float* Us3 = (const float*)d_in[5];  const float* ws3 = (const float*)d_in[6];
    const float* Up1 = (const float*)d_in[7];  const float* wp1 = (const float*)d_in[8];
    const float* Up2 = (const float*)d_in[9];  const float* wp2 = (const float*)d_in[10];
    const float* Up3 = (const float*)d_in[11]; const float* wp3 = (const float*)d_in[12];
    const float* Ud1 = (const float*)d_in[13]; const float* wd1 = (const float*)d_in[14];
    const float* Ud2 = (const float*)d_in[15]; const float* wd2 = (const float*)d_in[16];
    const float* Ud3 = (const float*)d_in[17]; const float* wd3 = (const float*)d_in[18];
    float* out = (float*)d_out;
    float* Wm  = (float*)d_ws;

    const bool use_ws = ws_size >= (size_t)CFEAT * NM * ROWF * sizeof(float);
    if (use_ws) {
        symcon_prep<<<dim3(CFEAT, 9), 256, 0, stream>>>(
            Us1, ws1, Us2, ws2, Us3, ws3, Up1, wp1, Up2, wp2, Up3, wp3,
            Ud1, wd1, Ud2, wd2, Ud3, wd3, Wm);
        symcon_hot<false><<<dim3(CFEAT, NODES / 512), 256, 0, stream>>>(
            A, Wm, Us1, ws1, Us2, ws2, Us3, ws3, Up1, wp1, Up2, wp2, Up3, wp3,
            Ud1, wd1, Ud2, wd2, Ud3, wd3, out);
    } else {
        symcon_hot<true><<<dim3(CFEAT, NODES / 512), 256, 0, stream>>>(
            A, nullptr, Us1, ws1, Us2, ws2, Us3, ws3, Up1, wp1, Up2, wp2, Up3, wp3,
            Ud1, wd1, Ud2, wd2, Ud3, wd3, out);
    }
}

// Round 4
// 37.910 us; speedup vs baseline: 4.7446x; 1.2275x over previous
//
#include <hip/hip_runtime.h>
#include <hip/hip_bf16.h>
#include <utility>

#define CFEAT 128
#define NODES 2048
#define NM    219            // 9 deg1 + 45 deg2 + 165 deg3 monomials
#define NSTEP 7              // K padded to 224 = 7*32

typedef __attribute__((ext_vector_type(8))) short short8;
typedef __attribute__((ext_vector_type(4))) float f32x4;

__device__ __forceinline__ short f2bf(float x) {
    union { __hip_bfloat16 b; short s; } cv;
    cv.b = __float2bfloat16(x);
    return cv.s;
}

// ---- monomial index -> (deg,i,j,l), i<=j<=l (constexpr-foldable) ----------
struct MIdx { int deg, i, j, l; };
__host__ __device__ constexpr MIdx decode_c(int idx) {
    if (idx < 9) return {1, idx, 0, 0};
    int t = idx - 9;
    for (int i = 0; i < 9; ++i)
        for (int j = i; j < 9; ++j) {
            int cnt = 10 - j;            // 1 deg2 + (9-j) deg3
            if (t < cnt) {
                if (t == 0) return {2, i, j, 0};
                return {3, i, j, j + t - 1};
            }
            t -= cnt;
        }
    return {0, 0, 0, 0};
}

template<int K>
__device__ __forceinline__ float mono_val_t(const float a[9]) {
    if constexpr (K >= NM) return 0.f;
    else {
        constexpr MIdx d = decode_c(K);
        if constexpr (d.deg == 1) return a[d.i];
        else if constexpr (d.deg == 2) return a[d.i] * a[d.j];
        else return a[d.i] * a[d.j] * a[d.l];
    }
}

template<int CHUNK, int... E>
__device__ __forceinline__ short8 packChunk(const float a[9], std::integer_sequence<int, E...>) {
    short8 pk{};
    ((pk[E] = f2bf(mono_val_t<CHUNK * 8 + E>(a))), ...);
    return pk;
}

// Build phi chunks [CCBASE, CCBASE+NCC) into my swizzled LDS row (bytes CC*16).
template<int CCBASE, int... CC>
__device__ __forceinline__ void buildPhiImpl(const float a[9], char* myrow, int swz,
                                             std::integer_sequence<int, CC...>) {
    ((*(short8*)(myrow + ((CC * 16) ^ swz)) =
          packChunk<CCBASE + CC>(a, std::make_integer_sequence<int, 8>{})), ...);
}
template<int CCBASE, int NCC>
__device__ __forceinline__ void buildPhi(const float a[9], char* myrow, int swz) {
    buildPhiImpl<CCBASE>(a, myrow, swz, std::make_integer_sequence<int, NCC>{});
}

// ---- weight-path helpers (fp32, same math as verified rounds 1-3) ---------
template<int K>
__device__ __forceinline__ float dotk(const float* __restrict__ u,
                                      const float* __restrict__ w, int c) {
    float s = 0.f;
    #pragma unroll
    for (int kk = 0; kk < K; ++kk) s = fmaf(u[kk], w[kk * CFEAT + c], s);
    return s;
}

template<int K2, int K3>
__device__ float mono_coeff(int deg, int i, int j, int l, int c, int ml,
    const float* __restrict__ U1, const float* __restrict__ w1,
    const float* __restrict__ U2, const float* __restrict__ w2,
    const float* __restrict__ U3, const float* __restrict__ w3)
{
    if (deg == 1) return U1[ml * 9 + i] * w1[c];              // k==1 for nu=1
    if (deg == 2) {
        float S = dotk<K2>(U2 + ((ml * 9 + i) * 9 + j) * K2, w2, c);
        if (i != j) S += dotk<K2>(U2 + ((ml * 9 + j) * 9 + i) * K2, w2, c);
        return S;
    }
    const int e0 = (i*9+j)*9+l, e1 = (i*9+l)*9+j, e2 = (j*9+i)*9+l,
              e3 = (j*9+l)*9+i, e4 = (l*9+i)*9+j, e5 = (l*9+j)*9+i;
    float S = dotk<K3>(U3 + (ml*729 + e0) * K3, w3, c);
    if (e1 != e0)                                           S += dotk<K3>(U3 + (ml*729+e1)*K3, w3, c);
    if (e2 != e0 && e2 != e1)                               S += dotk<K3>(U3 + (ml*729+e2)*K3, w3, c);
    if (e3 != e0 && e3 != e1 && e3 != e2)                   S += dotk<K3>(U3 + (ml*729+e3)*K3, w3, c);
    if (e4 != e0 && e4 != e1 && e4 != e2 && e4 != e3)       S += dotk<K3>(U3 + (ml*729+e4)*K3, w3, c);
    if (e5 != e0 && e5 != e1 && e5 != e2 && e5 != e3 && e5 != e4)
                                                            S += dotk<K3>(U3 + (ml*729+e5)*K3, w3, c);
    return S;
}

// ---- kernel 1: W in MFMA B-fragment layout, bf16 --------------------------
// Wf[c][step][lane][e] = W_c[k = step*32 + (lane>>4)*8 + e][m = lane&15]
__global__ __launch_bounds__(256) void symcon_prep(
    const float* __restrict__ Us1, const float* __restrict__ ws1,
    const float* __restrict__ Us2, const float* __restrict__ ws2,
    const float* __restrict__ Us3, const float* __restrict__ ws3,
    const float* __restrict__ Up1, const float* __restrict__ wp1,
    const float* __restrict__ Up2, const float* __restrict__ wp2,
    const float* __restrict__ Up3, const float* __restrict__ wp3,
    const float* __restrict__ Ud1, const float* __restrict__ wd1,
    const float* __restrict__ Ud2, const float* __restrict__ wd2,
    const float* __restrict__ Ud3, const float* __restrict__ wd3,
    short* __restrict__ Wf)
{
    const int c = blockIdx.x, step = blockIdx.y;
    for (int slot = threadIdx.x; slot < 512; slot += 256) {
        const int lane = slot >> 3, e = slot & 7;
        const int k = step * 32 + ((lane >> 4) * 8) + e;
        const int m = lane & 15;
        float v = 0.f;
        if (k < NM && m < 9) {
            MIdx d = decode_c(k);
            if (m == 0)
                v = mono_coeff<2,5>(d.deg, d.i, d.j, d.l, c, 0,     Us1, ws1, Us2, ws2, Us3, ws3);
            else if (m < 4)
                v = mono_coeff<3,8>(d.deg, d.i, d.j, d.l, c, m - 1, Up1, wp1, Up2, wp2, Up3, wp3);
            else
                v = mono_coeff<4,10>(d.deg, d.i, d.j, d.l, c, m - 4, Ud1, wd1, Ud2, wd2, Ud3, wd3);
        }
        Wf[(((size_t)c * NSTEP + step) * 64 + lane) * 8 + e] = f2bf(v);
    }
}

// ---- kernel 2: hot — wave-private 64-node x 1-channel GEMM tiles ----------
__global__ __launch_bounds__(256, 2) void symcon_hot(
    const float* __restrict__ A, const short* __restrict__ Wf,
    float* __restrict__ out)
{
    const int c   = blockIdx.x;
    const int grp = blockIdx.y;            // 0..7
    const int tid = threadIdx.x;
    const int w   = tid >> 6;              // wave 0..3
    const int l   = tid & 63;              // lane

    __shared__ __align__(16) char phiAll[4 * 16384];   // 16KB per wave, wave-private
    char* const phi = phiAll + w * 16384;

    // B fragments for this channel: lane l loads its 16B per step (coalesced)
    const short8* Wc = (const short8*)Wf + (size_t)c * NSTEP * 64;
    short8 bfrag[NSTEP];
    #pragma unroll
    for (int s = 0; s < NSTEP; ++s) bfrag[s] = Wc[s * 64 + l];

    // this wave's 64 nodes; lane l owns node nb+l
    const int nb = (grp * 4 + w) * 64;
    const float* Ap = A + ((size_t)(nb + l) * CFEAT + c) * 9;
    float a[9];
    #pragma unroll
    for (int q = 0; q < 9; ++q) a[q] = Ap[q];

    char* const myrow = phi + l * 256;     // row stride 256B (128 bf16 k-slots)
    const int swz = (l & 7) << 4;          // T2 XOR swizzle (16B granules)

    f32x4 acc[4];
    #pragma unroll
    for (int t = 0; t < 4; ++t) acc[t] = f32x4{0.f, 0.f, 0.f, 0.f};

    const int m  = l & 15;                 // N index (output m) / A-row within tile
    const int kg = l >> 4;                 // k-subgroup 0..3
    const int ko = kg * 16;                // byte offset of my 8 bf16 within a 32-k step

    // ---- half 0: k in [0,128) -> chunks 0..15, MFMA steps 0..3
    buildPhi<0, 16>(a, myrow, swz);
    #pragma unroll
    for (int t = 0; t < 4; ++t) {
        const int row = t * 16 + m;
        const char* rp = phi + row * 256;
        const int rsw = (row & 7) << 4;
        #pragma unroll
        for (int s = 0; s < 4; ++s) {
            short8 af = *(const short8*)(rp + ((s * 64 + ko) ^ rsw));
            acc[t] = __builtin_amdgcn_mfma_f32_16x16x32_bf16(af, bfrag[s], acc[t], 0, 0, 0);
        }
    }

    // ---- half 1: k in [128,224) -> chunks 16..27 (k>=219 zero-padded),
    // reusing bytes [0,192) of each row; same-wave DS ordering keeps this safe
    buildPhi<16, 12>(a, myrow, swz);
    #pragma unroll
    for (int t = 0; t < 4; ++t) {
        const int row = t * 16 + m;
        const char* rp = phi + row * 256;
        const int rsw = (row & 7) << 4;
        #pragma unroll
        for (int s = 0; s < 3; ++s) {
            short8 af = *(const short8*)(rp + ((s * 64 + ko) ^ rsw));
            acc[t] = __builtin_amdgcn_mfma_f32_16x16x32_bf16(af, bfrag[4 + s], acc[t], 0, 0, 0);
        }
    }

    // ---- C/D layout (m89-verified): col = lane&15 = m, row = (lane>>4)*4 + reg
    if (m < 9) {
        #pragma unroll
        for (int t = 0; t < 4; ++t) {
            const int node0 = nb + t * 16 + kg * 4;
            float* op = out + ((size_t)node0 * CFEAT + c) * 9 + m;
            #pragma unroll
            for (int r = 0; r < 4; ++r)
                op[(size_t)r * CFEAT * 9] = acc[t][r];
        }
    }
}

extern "C" void kernel_launch(void* const* d_in, const int* in_sizes, int n_in,
                              void* d_out, int out_size, void* d_ws, size_t ws_size,
                              hipStream_t stream)
{
    const float* A   = (const float*)d_in[0];
    const float* Us1 = (const float*)d_in[1];  const float* ws1 = (const float*)d_in[2];
    const float* Us2 = (const float*)d_in[3];  const float* ws2 = (const float*)d_in[4];
    const float* Us3 = (const float*)d_in[5];  const float* ws3 = (const float*)d_in[6];
    const float* Up1 = (const float*)d_in[7];  const float* wp1 = (const float*)d_in[8];
    const float* Up2 = (const float*)d_in[9];  const float* wp2 = (const float*)d_in[10];
    const float* Up3 = (const float*)d_in[11]; const float* wp3 = (const float*)d_in[12];
    const float* Ud1 = (const float*)d_in[13]; const float* wd1 = (const float*)d_in[14];
    const float* Ud2 = (const float*)d_in[15]; const float* wd2 = (const float*)d_in[16];
    const float* Ud3 = (const float*)d_in[17]; const float* wd3 = (const float*)d_in[18];
    float* out = (float*)d_out;
    short* Wf  = (short*)d_ws;   // 128*7*64*8*2 B = 917504 B (ws proven >= 1.79 MB)

    symcon_prep<<<dim3(CFEAT, NSTEP), 256, 0, stream>>>(
        Us1, ws1, Us2, ws2, Us3, ws3, Up1, wp1, Up2, wp2, Up3, wp3,
        Ud1, wd1, Ud2, wd2, Ud3, wd3, Wf);

    symcon_hot<<<dim3(CFEAT, NODES / 256), 256, 0, stream>>>(A, Wf, out);
}

// Round 5
// 31.130 us; speedup vs baseline: 5.7779x; 1.2178x over previous
//
#include <hip/hip_runtime.h>
#include <hip/hip_bf16.h>
#include <utility>

#define CFEAT 128
#define NODES 2048
#define NM    219            // 9 deg1 + 45 deg2 + 165 deg3 monomials
#define NSTEP 7              // K padded to 224 = 7*32

typedef __attribute__((ext_vector_type(8))) short short8;
typedef __attribute__((ext_vector_type(4))) float f32x4;

// ---- ws float offsets ------------------------------------------------------
// [0, 917504B): Wf bf16 fragments. Then (floats):
#define OFF3 262144                          // U3s [9][165][16]
#define OFF2 (OFF3 + 9*165*16)               // U2s [9][45][4]
#define OFF1 (OFF2 + 9*45*4)                 // U1s [9][9]

__device__ __forceinline__ short f2bf(float x) {
    union { __hip_bfloat16 b; short s; } cv;
    cv.b = __float2bfloat16(x);
    return cv.s;
}

// ---- monomial index -> (deg,i,j,l), i<=j<=l --------------------------------
struct MIdx { int deg, i, j, l; };
__host__ __device__ constexpr MIdx decode_c(int idx) {
    if (idx < 9) return {1, idx, 0, 0};
    int t = idx - 9;
    for (int i = 0; i < 9; ++i)
        for (int j = i; j < 9; ++j) {
            int cnt = 10 - j;
            if (t < cnt) {
                if (t == 0) return {2, i, j, 0};
                return {3, i, j, j + t - 1};
            }
            t -= cnt;
        }
    return {0, 0, 0, 0};
}

__device__ __forceinline__ int h2(int n) { return n * (n + 1) / 2; }
__device__ __forceinline__ int g3(int n) { return n * (n + 1) * (n + 2) / 6; }
// lexicographic index of triple (i<=j<=l) in [0,165)
__device__ __forceinline__ int tri3(int i, int j, int l) {
    return (165 - g3(9 - i)) + (h2(9 - i) - h2(9 - j)) + (l - j);
}
// lexicographic index of pair (i<=j) in [0,45)
__device__ __forceinline__ int pair2(int i, int j) {
    return (45 - h2(9 - i)) + (j - i);
}

template<int K>
__device__ __forceinline__ float mono_val_t(const float a[9]) {
    if constexpr (K >= NM) return 0.f;
    else {
        constexpr MIdx d = decode_c(K);
        if constexpr (d.deg == 1) return a[d.i];
        else if constexpr (d.deg == 2) return a[d.i] * a[d.j];
        else return a[d.i] * a[d.j] * a[d.l];
    }
}

template<int CHUNK, int... E>
__device__ __forceinline__ short8 packChunk(const float a[9], std::integer_sequence<int, E...>) {
    short8 pk{};
    ((pk[E] = f2bf(mono_val_t<CHUNK * 8 + E>(a))), ...);
    return pk;
}

// Build chunks [CCBASE, CCBASE+NCC) into LDS slots [0,NCC), key (slot&3)<<5.
template<int CCBASE, int... CC>
__device__ __forceinline__ void buildPhiImpl(const float a[9], char* const wb[4],
                                             std::integer_sequence<int, CC...>) {
    ((*(short8*)(wb[CC & 3] + CC * 1024) =
          packChunk<CCBASE + CC>(a, std::make_integer_sequence<int, 8>{})), ...);
}
template<int CCBASE, int NCC>
__device__ __forceinline__ void buildPhi(const float a[9], char* const wb[4]) {
    buildPhiImpl<CCBASE>(a, wb, std::make_integer_sequence<int, NCC>{});
}

// ---- P1: channel-independent symmetrization of U tensors -------------------
// grid (9, 12). y<11: deg3 triples [y*15, y*15+15). y==11: deg2 + deg1.
__global__ __launch_bounds__(256) void symcon_p1(
    const float* __restrict__ Us1, const float* __restrict__ Us2, const float* __restrict__ Us3,
    const float* __restrict__ Up1, const float* __restrict__ Up2, const float* __restrict__ Up3,
    const float* __restrict__ Ud1, const float* __restrict__ Ud2, const float* __restrict__ Ud3,
    float* __restrict__ ws_f)
{
    const int mg = blockIdx.x;           // 0=s, 1..3=p, 4..8=d
    const int y  = blockIdx.y;
    const int t  = threadIdx.x;

    const float *U1, *U2, *U3; int K2, K3, ml;
    if (mg == 0)     { U1 = Us1; U2 = Us2; U3 = Us3; K2 = 2; K3 = 5;  ml = 0; }
    else if (mg < 4) { U1 = Up1; U2 = Up2; U3 = Up3; K2 = 3; K3 = 8;  ml = mg - 1; }
    else             { U1 = Ud1; U2 = Ud2; U3 = Ud3; K2 = 4; K3 = 10; ml = mg - 4; }

    if (y < 11) {
        if (t >= 240) return;
        const int tri = y * 15 + (t >> 4);
        const int k   = t & 15;
        if (k >= K3) return;
        // invert tri -> (i,j,l)
        int i = 0, j = 0, l = 0, r = tri;
        bool done = false;
        for (i = 0; i < 9 && !done; ++i)
            for (j = i; j < 9; ++j) {
                int cnt = 9 - j;
                if (r < cnt) { l = j + r; done = true; break; }
                r -= cnt;
            }
        --i;  // loop incremented past
        const int e0=(i*9+j)*9+l, e1=(i*9+l)*9+j, e2=(j*9+i)*9+l,
                  e3=(j*9+l)*9+i, e4=(l*9+i)*9+j, e5=(l*9+j)*9+i;
        const float* B3 = U3 + (size_t)ml * 729 * K3 + k;
        float v = B3[(size_t)e0 * K3];
        if (e1 != e0)                                     v += B3[(size_t)e1 * K3];
        if (e2 != e0 && e2 != e1)                         v += B3[(size_t)e2 * K3];
        if (e3 != e0 && e3 != e1 && e3 != e2)             v += B3[(size_t)e3 * K3];
        if (e4 != e0 && e4 != e1 && e4 != e2 && e4 != e3) v += B3[(size_t)e4 * K3];
        if (e5 != e0 && e5 != e1 && e5 != e2 && e5 != e3 && e5 != e4)
                                                          v += B3[(size_t)e5 * K3];
        ws_f[OFF3 + (mg * 165 + tri) * 16 + k] = v;
    } else {
        if (t < 180) {
            int pr = t >> 2, k = t & 3;
            if (k >= K2) return;
            int i = 0, j = 0, r = pr;
            for (i = 0; i < 9; ++i) {
                int cnt = 9 - i;
                if (r < cnt) { j = i + r; break; }
                r -= cnt;
            }
            float v = U2[((size_t)(ml * 9 + i) * 9 + j) * K2 + k];
            if (i != j) v += U2[((size_t)(ml * 9 + j) * 9 + i) * K2 + k];
            ws_f[OFF2 + (mg * 45 + pr) * 4 + k] = v;
        } else if (t < 189) {
            const int i = t - 180;
            ws_f[OFF1 + mg * 9 + i] = U1[ml * 9 + i];
        }
    }
}

// ---- P2: per-channel weighting into bf16 B-fragment layout -----------------
// Wf[c][step][lane][e] = W_c[k = step*32 + (lane>>4)*8 + e][m = lane&15]
__global__ __launch_bounds__(256) void symcon_p2(
    const float* __restrict__ ws_f,
    const float* __restrict__ ws1, const float* __restrict__ ws2, const float* __restrict__ ws3,
    const float* __restrict__ wp1, const float* __restrict__ wp2, const float* __restrict__ wp3,
    const float* __restrict__ wd1, const float* __restrict__ wd2, const float* __restrict__ wd3,
    short* __restrict__ Wf)
{
    const int c = blockIdx.x, step = blockIdx.y;
    for (int slot = threadIdx.x; slot < 512; slot += 256) {
        const int lane = slot >> 3, e = slot & 7;
        const int k = step * 32 + ((lane >> 4) * 8) + e;
        const int m = lane & 15;
        float v = 0.f;
        if (k < NM && m < 9) {
            MIdx d = decode_c(k);
            const float *w1, *w2, *w3; int K2, K3;
            if (m == 0)     { w1 = ws1; w2 = ws2; w3 = ws3; K2 = 2; K3 = 5;  }
            else if (m < 4) { w1 = wp1; w2 = wp2; w3 = wp3; K2 = 3; K3 = 8;  }
            else            { w1 = wd1; w2 = wd2; w3 = wd3; K2 = 4; K3 = 10; }
            if (d.deg == 1) {
                v = ws_f[OFF1 + m * 9 + d.i] * w1[c];
            } else if (d.deg == 2) {
                const float* u = ws_f + OFF2 + (m * 45 + pair2(d.i, d.j)) * 4;
                for (int kk = 0; kk < K2; ++kk) v = fmaf(u[kk], w2[kk * CFEAT + c], v);
            } else {
                const float* u = ws_f + OFF3 + (m * 165 + tri3(d.i, d.j, d.l)) * 16;
                for (int kk = 0; kk < K3; ++kk) v = fmaf(u[kk], w3[kk * CFEAT + c], v);
            }
        }
        Wf[(((size_t)c * NSTEP + step) * 64 + lane) * 8 + e] = f2bf(v);
    }
}

// ---- hot: wave-private 64-node x 1-channel GEMM tiles ----------------------
// grid (32 cgroups, 32 ngroups); wave w -> channel cg*4+w, nodes ng*64..+64
__global__ __launch_bounds__(256, 2) void symcon_hot(
    const float* __restrict__ A, const short* __restrict__ Wf,
    float* __restrict__ out)
{
    const int tid = threadIdx.x;
    const int w   = tid >> 6;              // wave 0..3
    const int l   = tid & 63;              // lane

    __shared__ __align__(16) char phiAll[4 * 16384];   // 16KB per wave, wave-private
    char* const phi = phiAll + w * 16384;

    const int c  = blockIdx.x * 4 + w;
    const int nb = blockIdx.y * 64;

    // B fragments: lane l's 16B per 32-k step (coalesced 1KB/instr)
    const short8* Wc = (const short8*)Wf + (size_t)c * NSTEP * 64;
    short8 bfrag[NSTEP];
    #pragma unroll
    for (int s = 0; s < NSTEP; ++s) bfrag[s] = Wc[s * 64 + l];

    // lane l owns node nb+l
    const float* Ap = A + ((size_t)(nb + l) * CFEAT + c) * 9;
    float a[9];
    #pragma unroll
    for (int q = 0; q < 9; ++q) a[q] = Ap[q];

    // write bases: slot's 16B for lane l at granule (l ^ ((slot&3)<<1))
    char* wb[4];
    #pragma unroll
    for (int kk = 0; kk < 4; ++kk) wb[kk] = phi + ((l * 16) ^ (kk << 5));

    // read base: lane (m,kg) reads slot s*4+kg, row t*16+m, same XOR key
    const int m  = l & 15;
    const int kg = l >> 4;
    const char* rb = phi + kg * 1024 + ((m * 16) ^ (kg << 5));

    f32x4 acc[4];
    #pragma unroll
    for (int t = 0; t < 4; ++t) acc[t] = f32x4{0.f, 0.f, 0.f, 0.f};

    // ---- half 0: k in [0,128): chunks 0..15 -> slots 0..15, steps 0..3
    buildPhi<0, 16>(a, wb);
    #pragma unroll
    for (int t = 0; t < 4; ++t)
        #pragma unroll
        for (int s = 0; s < 4; ++s) {
            short8 af = *(const short8*)(rb + s * 4096 + t * 256);
            acc[t] = __builtin_amdgcn_mfma_f32_16x16x32_bf16(af, bfrag[s], acc[t], 0, 0, 0);
        }

    // ---- half 1: k in [128,224): chunks 16..27 -> slots 0..11, steps 4..6
    buildPhi<16, 12>(a, wb);
    #pragma unroll
    for (int t = 0; t < 4; ++t)
        #pragma unroll
        for (int s = 0; s < 3; ++s) {
            short8 af = *(const short8*)(rb + s * 4096 + t * 256);
            acc[t] = __builtin_amdgcn_mfma_f32_16x16x32_bf16(af, bfrag[4 + s], acc[t], 0, 0, 0);
        }

    // C/D layout (m89): col = lane&15 = m, row = (lane>>4)*4 + reg
    if (m < 9) {
        #pragma unroll
        for (int t = 0; t < 4; ++t) {
            const int node0 = nb + t * 16 + kg * 4;
            float* op = out + ((size_t)node0 * CFEAT + c) * 9 + m;
            #pragma unroll
            for (int r = 0; r < 4; ++r)
                op[(size_t)r * CFEAT * 9] = acc[t][r];
        }
    }
}

extern "C" void kernel_launch(void* const* d_in, const int* in_sizes, int n_in,
                              void* d_out, int out_size, void* d_ws, size_t ws_size,
                              hipStream_t stream)
{
    const float* A   = (const float*)d_in[0];
    const float* Us1 = (const float*)d_in[1];  const float* ws1 = (const float*)d_in[2];
    const float* Us2 = (const float*)d_in[3];  const float* ws2 = (const float*)d_in[4];
    const float* Us3 = (const float*)d_in[5];  const float* ws3 = (const float*)d_in[6];
    const float* Up1 = (const float*)d_in[7];  const float* wp1 = (const float*)d_in[8];
    const float* Up2 = (const float*)d_in[9];  const float* wp2 = (const float*)d_in[10];
    const float* Up3 = (const float*)d_in[11]; const float* wp3 = (const float*)d_in[12];
    const float* Ud1 = (const float*)d_in[13]; const float* wd1 = (const float*)d_in[14];
    const float* Ud2 = (const float*)d_in[15]; const float* wd2 = (const float*)d_in[16];
    const float* Ud3 = (const float*)d_in[17]; const float* wd3 = (const float*)d_in[18];
    float* out  = (float*)d_out;
    float* ws_f = (float*)d_ws;
    short* Wf   = (short*)d_ws;

    symcon_p1<<<dim3(9, 12), 256, 0, stream>>>(
        Us1, Us2, Us3, Up1, Up2, Up3, Ud1, Ud2, Ud3, ws_f);

    symcon_p2<<<dim3(CFEAT, NSTEP), 256, 0, stream>>>(
        ws_f, ws1, ws2, ws3, wp1, wp2, wp3, wd1, wd2, wd3, Wf);

    symcon_hot<<<dim3(CFEAT / 4, NODES / 64), 256, 0, stream>>>(A, Wf, out);
}

// Round 6
// 31.001 us; speedup vs baseline: 5.8021x; 1.0042x over previous
//
#include <hip/hip_runtime.h>
#include <hip/hip_bf16.h>

#define CFEAT 128
#define NODES 2048
#define NM    219            // 9 deg1 + 45 deg2 + 165 deg3 monomials
#define NSTEP 7              // K padded to 224 = 7*32

typedef __attribute__((ext_vector_type(8))) short short8;
typedef __attribute__((ext_vector_type(4))) float f32x4;
typedef __attribute__((ext_vector_type(4))) unsigned int uint4v;

// ---- ws float offsets: [0, 917504B) = Wf bf16 fragments, then: ------------
#define OFF3 262144                          // U3s [9][165][16]
#define OFF2 (OFF3 + 9*165*16)               // U2s [9][45][4]
#define OFF1 (OFF2 + 9*45*4)                 // U1s [9][9]

__device__ __forceinline__ short f2bf(float x) {
    union { __hip_bfloat16 b; short s; } cv;
    cv.b = __float2bfloat16(x);
    return cv.s;
}

// ---- monomial index -> (deg,i,j,l), i<=j<=l (constexpr) --------------------
struct MIdx { int deg, i, j, l; };
__host__ __device__ constexpr MIdx decode_c(int idx) {
    if (idx < 9) return {1, idx, 0, 0};
    int t = idx - 9;
    for (int i = 0; i < 9; ++i)
        for (int j = i; j < 9; ++j) {
            int cnt = 10 - j;
            if (t < cnt) {
                if (t == 0) return {2, i, j, 0};
                return {3, i, j, j + t - 1};
            }
            t -= cnt;
        }
    return {0, 0, 0, 0};
}
__host__ __device__ constexpr int h2c(int n) { return n * (n + 1) / 2; }
__host__ __device__ constexpr int g3c(int n) { return n * (n + 1) * (n + 2) / 6; }
__host__ __device__ constexpr int tri3c(int i, int j, int l) {
    return (165 - g3c(9 - i)) + (h2c(9 - i) - h2c(9 - j)) + (l - j);
}
__host__ __device__ constexpr int pair2c(int i, int j) {
    return (45 - h2c(9 - i)) + (j - i);
}

// packed per-k table: deg | (sub-index << 4)  (sub = i / pair2 / tri3)
struct MTbl { int v[224]; };
__host__ __device__ constexpr MTbl gen_tbl() {
    MTbl t{};
    for (int k = 0; k < 224; ++k) {
        if (k < NM) {
            MIdx d = decode_c(k);
            int sub = (d.deg == 1) ? d.i : (d.deg == 2) ? pair2c(d.i, d.j)
                                                        : tri3c(d.i, d.j, d.l);
            t.v[k] = d.deg | (sub << 4);
        } else t.v[k] = 0;
    }
    return t;
}
__device__ constexpr MTbl MONO_TBL = gen_tbl();

template<int K>
__device__ __forceinline__ float mono_val_t(const float a[9]) {
    if constexpr (K >= NM) return 0.f;
    else {
        constexpr MIdx d = decode_c(K);
        if constexpr (d.deg == 1) return a[d.i];
        else if constexpr (d.deg == 2) return a[d.i] * a[d.j];
        else return a[d.i] * a[d.j] * a[d.l];
    }
}

// pack two monomials to 2xbf16 in one dword: round-half-up + v_perm hi16 merge
template<int KB, int E2>
__device__ __forceinline__ unsigned pack2(const float a[9]) {
    const float lo = mono_val_t<KB + 2 * E2>(a);
    const float hi = mono_val_t<KB + 2 * E2 + 1>(a);
    return __builtin_amdgcn_perm(__float_as_uint(hi) + 0x8000u,
                                 __float_as_uint(lo) + 0x8000u, 0x07060302u);
}
template<int KB>
__device__ __forceinline__ uint4v build_granule(const float a[9]) {
    return uint4v{pack2<KB,0>(a), pack2<KB,1>(a), pack2<KB,2>(a), pack2<KB,3>(a)};
}

// ---- P1: channel-independent symmetrization (verbatim from round 5) -------
__global__ __launch_bounds__(256) void symcon_p1(
    const float* __restrict__ Us1, const float* __restrict__ Us2, const float* __restrict__ Us3,
    const float* __restrict__ Up1, const float* __restrict__ Up2, const float* __restrict__ Up3,
    const float* __restrict__ Ud1, const float* __restrict__ Ud2, const float* __restrict__ Ud3,
    float* __restrict__ ws_f)
{
    const int mg = blockIdx.x;
    const int y  = blockIdx.y;
    const int t  = threadIdx.x;

    const float *U1, *U2, *U3; int K2, K3, ml;
    if (mg == 0)     { U1 = Us1; U2 = Us2; U3 = Us3; K2 = 2; K3 = 5;  ml = 0; }
    else if (mg < 4) { U1 = Up1; U2 = Up2; U3 = Up3; K2 = 3; K3 = 8;  ml = mg - 1; }
    else             { U1 = Ud1; U2 = Ud2; U3 = Ud3; K2 = 4; K3 = 10; ml = mg - 4; }

    if (y < 11) {
        if (t >= 240) return;
        const int tri = y * 15 + (t >> 4);
        const int k   = t & 15;
        if (k >= K3) return;
        int i = 0, j = 0, l = 0, r = tri;
        bool done = false;
        for (i = 0; i < 9 && !done; ++i)
            for (j = i; j < 9; ++j) {
                int cnt = 9 - j;
                if (r < cnt) { l = j + r; done = true; break; }
                r -= cnt;
            }
        --i;
        const int e0=(i*9+j)*9+l, e1=(i*9+l)*9+j, e2=(j*9+i)*9+l,
                  e3=(j*9+l)*9+i, e4=(l*9+i)*9+j, e5=(l*9+j)*9+i;
        const float* B3 = U3 + (size_t)ml * 729 * K3 + k;
        float v = B3[(size_t)e0 * K3];
        if (e1 != e0)                                     v += B3[(size_t)e1 * K3];
        if (e2 != e0 && e2 != e1)                         v += B3[(size_t)e2 * K3];
        if (e3 != e0 && e3 != e1 && e3 != e2)             v += B3[(size_t)e3 * K3];
        if (e4 != e0 && e4 != e1 && e4 != e2 && e4 != e3) v += B3[(size_t)e4 * K3];
        if (e5 != e0 && e5 != e1 && e5 != e2 && e5 != e3 && e5 != e4)
                                                          v += B3[(size_t)e5 * K3];
        ws_f[OFF3 + (mg * 165 + tri) * 16 + k] = v;
    } else {
        if (t < 180) {
            int pr = t >> 2, k = t & 3;
            if (k >= K2) return;
            int i = 0, j = 0, r = pr;
            for (i = 0; i < 9; ++i) {
                int cnt = 9 - i;
                if (r < cnt) { j = i + r; break; }
                r -= cnt;
            }
            float v = U2[((size_t)(ml * 9 + i) * 9 + j) * K2 + k];
            if (i != j) v += U2[((size_t)(ml * 9 + j) * 9 + i) * K2 + k];
            ws_f[OFF2 + (mg * 45 + pr) * 4 + k] = v;
        } else if (t < 189) {
            const int i = t - 180;
            ws_f[OFF1 + mg * 9 + i] = U1[ml * 9 + i];
        }
    }
}

// ---- P2: per-channel weighting into bf16 B-fragment layout -----------------
__global__ __launch_bounds__(256) void symcon_p2(
    const float* __restrict__ ws_f,
    const float* __restrict__ ws1, const float* __restrict__ ws2, const float* __restrict__ ws3,
    const float* __restrict__ wp1, const float* __restrict__ wp2, const float* __restrict__ wp3,
    const float* __restrict__ wd1, const float* __restrict__ wd2, const float* __restrict__ wd3,
    short* __restrict__ Wf)
{
    const int c = blockIdx.x, step = blockIdx.y;
    for (int slot = threadIdx.x; slot < 512; slot += 256) {
        const int lane = slot >> 3, e = slot & 7;
        const int k = step * 32 + ((lane >> 4) * 8) + e;
        const int m = lane & 15;
        float v = 0.f;
        if (k < NM && m < 9) {
            const int pk  = MONO_TBL.v[k];
            const int deg = pk & 15, sub = pk >> 4;
            const float *w1, *w2, *w3; int K2, K3;
            if (m == 0)     { w1 = ws1; w2 = ws2; w3 = ws3; K2 = 2; K3 = 5;  }
            else if (m < 4) { w1 = wp1; w2 = wp2; w3 = wp3; K2 = 3; K3 = 8;  }
            else            { w1 = wd1; w2 = wd2; w3 = wd3; K2 = 4; K3 = 10; }
            if (deg == 1) {
                v = ws_f[OFF1 + m * 9 + sub] * w1[c];
            } else if (deg == 2) {
                const float* u = ws_f + OFF2 + (m * 45 + sub) * 4;
                for (int kk = 0; kk < K2; ++kk) v = fmaf(u[kk], w2[kk * CFEAT + c], v);
            } else {
                const float* u = ws_f + OFF3 + (m * 165 + sub) * 16;
                for (int kk = 0; kk < K3; ++kk) v = fmaf(u[kk], w3[kk * CFEAT + c], v);
            }
        }
        Wf[(((size_t)c * NSTEP + step) * 64 + lane) * 8 + e] = f2bf(v);
    }
}

// ---- hot: one K-step at a time through a 4KB wave-private phi buffer -------
template<int S>
__device__ __forceinline__ void do_step(const float a[9], char* wrbase, const char* rdbase,
                                        const short8 bfrag[NSTEP], f32x4 acc[4])
{
    const uint4v g0 = build_granule<S * 32 +  0>(a);
    const uint4v g1 = build_granule<S * 32 +  8>(a);
    const uint4v g2 = build_granule<S * 32 + 16>(a);
    const uint4v g3 = build_granule<S * 32 + 24>(a);
    *(uint4v*)(wrbase         ) = g0;
    *(uint4v*)(wrbase + 1024  ) = g1;
    *(uint4v*)(wrbase + 2048  ) = g2;
    *(uint4v*)(wrbase + 3072  ) = g3;
    #pragma unroll
    for (int t = 0; t < 4; ++t) {
        short8 af = *(const short8*)(rdbase + t * 256);
        acc[t] = __builtin_amdgcn_mfma_f32_16x16x32_bf16(af, bfrag[S], acc[t], 0, 0, 0);
    }
}

__global__ __launch_bounds__(256, 4) void symcon_hot(
    const float* __restrict__ A, const short* __restrict__ Wf, float* __restrict__ out)
{
    const int tid = threadIdx.x;
    const int w = tid >> 6, l = tid & 63;
    const int p = l & 15, q = l >> 4;
    const int c0 = blockIdx.x * 4;     // 4 adjacent channels per block
    const int nb = blockIdx.y * 64;    // 64 nodes per block

    __shared__ float sA[64 * 37];                     // 9472 B: A in / out staging (pad 37)
    __shared__ __align__(16) char phiAll[4 * 4096];   // 4KB per wave, wave-private

    // B fragments for channel c0+w (L2-resident, b128 coalesced)
    const short8* Wc = (const short8*)Wf + (size_t)(c0 + w) * NSTEP * 64;
    short8 bfrag[NSTEP];
    #pragma unroll
    for (int s = 0; s < NSTEP; ++s) bfrag[s] = Wc[s * 64 + l];

    // cooperative A stage: 64 nodes x 36 contiguous floats (4 channels)
    const size_t gbase = (size_t)nb * (CFEAT * 9) + (size_t)c0 * 9;
    #pragma unroll
    for (int e = tid; e < 64 * 36; e += 256) {
        const int n = e / 36, f = e - n * 36;
        sA[n * 37 + f] = A[gbase + (size_t)n * (CFEAT * 9) + f];
    }
    __syncthreads();

    // lane l's node vector for its wave's channel slot (2-way max, free)
    float a[9];
    #pragma unroll
    for (int x = 0; x < 9; ++x) a[x] = sA[l * 37 + w * 9 + x];

    char* const phiW   = phiAll + w * 4096;
    char* const wrbase = phiW + l * 16;            // write: chunk cc at +cc*1024
    const char* const rdbase = phiW + q * 1024 + p * 16;  // read: tile t at +t*256

    f32x4 acc[4];
    #pragma unroll
    for (int t = 0; t < 4; ++t) acc[t] = f32x4{0.f, 0.f, 0.f, 0.f};

    do_step<0>(a, wrbase, rdbase, bfrag, acc);
    do_step<1>(a, wrbase, rdbase, bfrag, acc);
    do_step<2>(a, wrbase, rdbase, bfrag, acc);
    do_step<3>(a, wrbase, rdbase, bfrag, acc);
    do_step<4>(a, wrbase, rdbase, bfrag, acc);
    do_step<5>(a, wrbase, rdbase, bfrag, acc);
    do_step<6>(a, wrbase, rdbase, bfrag, acc);

    // C/D (m89): col = l&15 = output m, row = q*4 + reg = node-within-tile.
    // Write into own wave's channel slot of sA (disjoint from other waves).
    if (p < 9) {
        #pragma unroll
        for (int t = 0; t < 4; ++t)
            #pragma unroll
            for (int r = 0; r < 4; ++r)
                sA[(t * 16 + q * 4 + r) * 37 + w * 9 + p] = acc[t][r];
    }
    __syncthreads();

    // cooperative store: dense 144B per node
    #pragma unroll
    for (int e = tid; e < 64 * 36; e += 256) {
        const int n = e / 36, f = e - n * 36;
        out[gbase + (size_t)n * (CFEAT * 9) + f] = sA[n * 37 + f];
    }
}

extern "C" void kernel_launch(void* const* d_in, const int* in_sizes, int n_in,
                              void* d_out, int out_size, void* d_ws, size_t ws_size,
                              hipStream_t stream)
{
    const float* A   = (const float*)d_in[0];
    const float* Us1 = (const float*)d_in[1];  const float* ws1 = (const float*)d_in[2];
    const float* Us2 = (const float*)d_in[3];  const float* ws2 = (const float*)d_in[4];
    const float* Us3 = (const float*)d_in[5];  const float* ws3 = (const float*)d_in[6];
    const float* Up1 = (const float*)d_in[7];  const float* wp1 = (const float*)d_in[8];
    const float* Up2 = (const float*)d_in[9];  const float* wp2 = (const float*)d_in[10];
    const float* Up3 = (const float*)d_in[11]; const float* wp3 = (const float*)d_in[12];
    const float* Ud1 = (const float*)d_in[13]; const float* wd1 = (const float*)d_in[14];
    const float* Ud2 = (const float*)d_in[15]; const float* wd2 = (const float*)d_in[16];
    const float* Ud3 = (const float*)d_in[17]; const float* wd3 = (const float*)d_in[18];
    float* out  = (float*)d_out;
    float* ws_f = (float*)d_ws;
    short* Wf   = (short*)d_ws;

    symcon_p1<<<dim3(9, 12), 256, 0, stream>>>(
        Us1, Us2, Us3, Up1, Up2, Up3, Ud1, Ud2, Ud3, ws_f);

    symcon_p2<<<dim3(CFEAT, NSTEP), 256, 0, stream>>>(
        ws_f, ws1, ws2, ws3, wp1, wp2, wp3, wd1, wd2, wd3, Wf);

    symcon_hot<<<dim3(CFEAT / 4, NODES / 64), 256, 0, stream>>>(A, Wf, out);
}